// Round 1
// baseline (8372.643 us; speedup 1.0000x reference)
//
#include <hip/hip_runtime.h>
#include <hip/hip_fp16.h>

// BiGRU persistent-kernel, round 4: coalesced publishes + per-wave barrier exit.
// B=64, T=512, D=256, U=512. 128 persistent blocks = 2 dirs x 64 unit-slices.
// Weights in VGPRs as fp16 MFMA B-fragments. Two global sync phases per step.
//
// R3 (6649us) theory: ~6.5us/exchange, dominated by (a) vmcnt(0) drain of 512
// scattered 2B agent write-through stores per block per phase (each its own IC
// transaction) and (b) two block-wide __syncthreads in bar_wait + unthrottled
// polling. R4: (a) per-wave LDS transpose bounce -> 32 lanes x 8B agent atomic
// stores (4x fewer IC transactions, row-contiguous 16B); out[] stores become
// 16B dwordx4 in the overlap window. (b) all 4 waves poll flags themselves
// (one coalesced 256B agent load/round) + per-wave acquire -> no __syncthreads
// in the wait path; s_sleep(1) backoff cuts poll pressure on the IC.
// Global protocol (flag array, monotonic counters, acquire->buffer_inv) is
// unchanged from the verified R3 kernel.

#define BB 64
#define TT 512
#define DD 256
#define UU 512
#define NBD 64        // blocks per direction
#define NJ 8          // units per block (NBD*NJ == UU)
#define LD3U (3*UU)

typedef _Float16 half8 __attribute__((ext_vector_type(8)));
typedef float floatx4 __attribute__((ext_vector_type(4)));
typedef unsigned long long u64;

// ---------------- setup: x -> fp16 [T][B][D]; zero h16 + barrier flags ------
__global__ void bigru_setup(const float* __restrict__ x, __half* __restrict__ x16,
                            __half* __restrict__ h16, unsigned* __restrict__ bars) {
    long idx = (long)blockIdx.x * blockDim.x + threadIdx.x;
    if (idx < (long)TT * BB * DD) {
        int t = (int)(idx / (BB * DD));
        int r = (int)(idx % (BB * DD));
        int b = r / DD;
        int d = r % DD;
        x16[idx] = __float2half(x[((long)b * TT + t) * DD + d]);
    }
    if (idx < 2 * 2 * BB * UU) h16[idx] = __float2half(0.0f);  // both parities, both dirs
    if (idx < 1024) bars[idx] = 0u;                            // both dirs' flag arrays
}

// ---- barrier halves (flag array, no RMW) -----------------------------------
__device__ __forceinline__ void bar_arrive(unsigned* flags, int s, unsigned p) {
    // Drain each wave's publishes (ack from IC), then one flag store per block.
    asm volatile("s_waitcnt vmcnt(0)" ::: "memory");
    __syncthreads();
    if (threadIdx.x == 0)
        __hip_atomic_store(&flags[s], p, __ATOMIC_RELAXED, __HIP_MEMORY_SCOPE_AGENT);
}

__device__ __forceinline__ void bar_wait(unsigned* flags, unsigned p, int lane) {
    // Every wave polls: lane i watches flags[i]; one coalesced 256B agent load
    // per round. Per-wave acquire (buffer_inv) so this wave's subsequent plain
    // vector loads see IC-fresh data. No block-wide sync needed: all post-wait
    // consumption is per-wave.
    for (;;) {
        unsigned v = __hip_atomic_load(&flags[lane], __ATOMIC_RELAXED,
                                       __HIP_MEMORY_SCOPE_AGENT);
        if (__ballot(v < p) == 0ull) break;
        __builtin_amdgcn_s_sleep(1);
    }
    (void)__hip_atomic_load(&flags[0], __ATOMIC_ACQUIRE, __HIP_MEMORY_SCOPE_AGENT);
}

// ---------------- persistent BiGRU kernel -----------------------------------
__global__ __launch_bounds__(256, 1) void bigru_persistent(
    const __half* __restrict__ x16,
    const float* __restrict__ Wx_f, const float* __restrict__ Wh_f, const float* __restrict__ b_f,
    const float* __restrict__ Wx_b, const float* __restrict__ Wh_b, const float* __restrict__ b_b,
    __half* __restrict__ h16,    // [parity][dir][B][U] fp16
    __half* __restrict__ rh16,   // [dir][B][U] fp16
    unsigned* __restrict__ bars, // flags: dir0 at [0..64), dir1 at [256..320)
    float* __restrict__ out)     // [B][T][2U] fp32
{
    const int blk  = blockIdx.x;
    const int dir  = blk / NBD;          // 0 = forward, 1 = backward
    const int s    = blk % NBD;
    const int j0   = s * NJ;
    const int tid  = threadIdx.x;
    const int wave = tid >> 6;
    const int lane = tid & 63;
    const int n    = lane & 15;          // MFMA col (C-layout) / A-row (A-layout)
    const int quad = lane >> 4;
    const int mbase = wave * 16;         // this wave's batch-row tile
    const int arow  = mbase + n;         // row this lane loads for A-fragments
    const int koff  = quad * 8;          // k-offset within a K=32 fragment

    const float* Wx = dir ? Wx_b : Wx_f;
    const float* Wh = dir ? Wh_b : Wh_f;
    const float* bv = dir ? b_b  : b_f;

    // Per-wave LDS bounce tiles: transpose lane-scattered gate outputs into
    // row-contiguous 16B chunks for coalesced wide publishes.
    __shared__ __half lds_rh[4][16][8];   // 1KB: r*h fp16 per wave
    __shared__ __half lds_h[4][16][8];    // 1KB: h fp16 per wave
    __shared__ float  lds_out[4][16][8];  // 2KB: h fp32 for out[]

    // ---- one-time: load weight fragments into registers (fp16) ----
    // Phase-A tile packs u-gate (cols 0..7 -> unit j0+n) and r-gate (cols 8..15).
    half8 WA[24];  // [x;h] @ W(:,u|r), K=768
    half8 W3[8];   // x @ Wx(:,c),      K=256 (cols n>=8 zero-padded)
    half8 WC[16];  // rh @ Wh(:,c),     K=512 (cols n>=8 zero-padded)
    const int colur = (n < 8) ? (j0 + n) : (UU + j0 + (n - 8));
#pragma unroll
    for (int f = 0; f < 24; ++f) {
        const int kb = f * 32 + koff;
#pragma unroll
        for (int kk = 0; kk < 8; ++kk) {
            const int k = kb + kk;
            float v = (k < DD) ? Wx[(long)k * LD3U + colur]
                               : Wh[(long)(k - DD) * LD3U + colur];
            WA[f][kk] = (_Float16)v;
        }
    }
#pragma unroll
    for (int f = 0; f < 8; ++f) {
        const int kb = f * 32 + koff;
#pragma unroll
        for (int kk = 0; kk < 8; ++kk) {
            float v = (n < 8) ? Wx[(long)(kb + kk) * LD3U + 2 * UU + j0 + n] : 0.0f;
            W3[f][kk] = (_Float16)v;
        }
    }
#pragma unroll
    for (int f = 0; f < 16; ++f) {
        const int kb = f * 32 + koff;
#pragma unroll
        for (int kk = 0; kk < 8; ++kk) {
            float v = (n < 8) ? Wh[(long)(kb + kk) * LD3U + 2 * UU + j0 + n] : 0.0f;
            WC[f][kk] = (_Float16)v;
        }
    }
    const float bias_ur = (n < 8) ? bv[j0 + n] : bv[UU + j0 + (n - 8)];
    const float bias_c  = (n < 8) ? bv[2 * UU + j0 + n] : 0.0f;

    // h slice owned by this lane (fp32): h[mbase+quad*4+i][j0+n] for n<8
    float h_own[4] = {0.f, 0.f, 0.f, 0.f};
    float u_keep[4] = {0.f, 0.f, 0.f, 0.f};

    unsigned* flags = bars + dir * 256;
    __half* rhb = rh16 + (long)dir * BB * UU;

    // Prologue: x fragments for t=0 + their h-independent MFMAs.
    floatx4 acc_ur = {0.f, 0.f, 0.f, 0.f};
    floatx4 acc_c  = {0.f, 0.f, 0.f, 0.f};
    half8 axx[8];
    {
        const int tx0 = dir ? (TT - 1) : 0;
        const __half* xrow = x16 + ((long)tx0 * BB + arow) * DD + koff;
#pragma unroll
        for (int f = 0; f < 8; ++f) axx[f] = *(const half8*)(xrow + f * 32);
#pragma unroll
        for (int f = 0; f < 8; ++f) {
            acc_ur = __builtin_amdgcn_mfma_f32_16x16x32_f16(axx[f], WA[f], acc_ur, 0, 0, 0);
            acc_c  = __builtin_amdgcn_mfma_f32_16x16x32_f16(axx[f], W3[f], acc_c, 0, 0, 0);
        }
    }

    for (int t = 0; t < TT; ++t) {
        // ---------------- Phase A (critical path: h-part only) ----------------
        const __half* hin = h16 + (long)((t & 1) * 2 + dir) * BB * UU;
        const __half* hrow = hin + (long)arow * UU + koff;
        half8 ah[16];
#pragma unroll
        for (int f = 0; f < 16; ++f) ah[f] = *(const half8*)(hrow + f * 32);
#pragma unroll
        for (int f = 0; f < 16; ++f)
            acc_ur = __builtin_amdgcn_mfma_f32_16x16x32_f16(ah[f], WA[8 + f], acc_ur, 0, 0, 0);

        // gates: lane(quad,n) holds rows mbase+quad*4+i, col n
#pragma unroll
        for (int i = 0; i < 4; ++i) {
            const float pre = acc_ur[i] + bias_ur;
            const float sg = 1.0f / (1.0f + __expf(-pre));
            // r-lanes (n>=8) need h_own from lane-8 (same quad, col n-8)
            const int src = (n >= 8) ? (lane - 8) : lane;
            const float hov = __shfl(h_own[i], src);
            if (n >= 8) {
                lds_rh[wave][quad * 4 + i][n - 8] = __float2half(sg * hov);
            } else {
                u_keep[i] = sg;
            }
        }
        // In-wave transpose bounce -> coalesced 8B agent publishes.
        asm volatile("s_waitcnt lgkmcnt(0)" ::: "memory");
        __builtin_amdgcn_sched_barrier(0);
        if (lane < 32) {
            const int r = lane >> 1, hh2 = lane & 1;
            const u64 v = *(const u64*)&lds_rh[wave][r][hh2 * 4];
            __hip_atomic_store((u64*)&rhb[(long)(mbase + r) * UU + j0 + hh2 * 4], v,
                               __ATOMIC_RELAXED, __HIP_MEMORY_SCOPE_AGENT);
        }
        bar_arrive(flags, s, 2u * (unsigned)t + 1u);
        bar_wait(flags, 2u * (unsigned)t + 1u, lane);

        // ---------------- Phase B ----------------
        const __half* rrow = rhb + (long)arow * UU + koff;
        half8 arh[16];
#pragma unroll
        for (int f = 0; f < 16; ++f) arh[f] = *(const half8*)(rrow + f * 32);
#pragma unroll
        for (int f = 0; f < 16; ++f)
            acc_c = __builtin_amdgcn_mfma_f32_16x16x32_f16(arh[f], WC[f], acc_c, 0, 0, 0);

        __half* hout = h16 + (long)(((t + 1) & 1) * 2 + dir) * BB * UU;
        if (n < 8) {
#pragma unroll
            for (int i = 0; i < 4; ++i) {
                float pre = acc_c[i] + bias_c;
                pre = fminf(fmaxf(pre, -15.0f), 15.0f);
                const float e2 = __expf(2.0f * pre);
                const float hh = (e2 - 1.0f) / (e2 + 1.0f);
                const float hn = (1.0f - u_keep[i]) * h_own[i] + u_keep[i] * hh;
                h_own[i] = hn;
                lds_h[wave][quad * 4 + i][n] = __float2half(hn);
                lds_out[wave][quad * 4 + i][n] = hn;
            }
        }
        asm volatile("s_waitcnt lgkmcnt(0)" ::: "memory");
        __builtin_amdgcn_sched_barrier(0);
        if (lane < 32) {
            const int r = lane >> 1, hh2 = lane & 1;
            const u64 v = *(const u64*)&lds_h[wave][r][hh2 * 4];
            __hip_atomic_store((u64*)&hout[(long)(mbase + r) * UU + j0 + hh2 * 4], v,
                               __ATOMIC_RELAXED, __HIP_MEMORY_SCOPE_AGENT);
        }

        const bool last = (t == TT - 1);
        if (!last) bar_arrive(flags, s, 2u * (unsigned)t + 2u);

        // ---- overlap window (hides the wait for other blocks' h publishes) ----
        {
            // Prefetch x(t+1) first (longest latency, independent).
            const int tn = last ? t : (t + 1);
            const int txn = dir ? (TT - 1 - tn) : tn;
            const __half* xrow = x16 + ((long)txn * BB + arow) * DD + koff;
#pragma unroll
            for (int f = 0; f < 8; ++f) axx[f] = *(const half8*)(xrow + f * 32);

            // out[] store: coalesced 16B rows from the fp32 LDS tile.
            if (lane < 32) {
                const int r = lane >> 1, hh2 = lane & 1;
                const int row = mbase + r;
                *(floatx4*)&out[((long)row * TT + t) * (2 * UU) + (long)dir * UU + j0 + hh2 * 4]
                    = *(const floatx4*)&lds_out[wave][r][hh2 * 4];
            }

            // h-independent MFMAs for t+1.
            floatx4 nacc_ur = {0.f, 0.f, 0.f, 0.f};
            floatx4 nacc_c  = {0.f, 0.f, 0.f, 0.f};
#pragma unroll
            for (int f = 0; f < 8; ++f) {
                nacc_ur = __builtin_amdgcn_mfma_f32_16x16x32_f16(axx[f], WA[f], nacc_ur, 0, 0, 0);
                nacc_c  = __builtin_amdgcn_mfma_f32_16x16x32_f16(axx[f], W3[f], nacc_c, 0, 0, 0);
            }
            acc_ur = nacc_ur;
            acc_c  = nacc_c;
        }

        if (!last) bar_wait(flags, 2u * (unsigned)t + 2u, lane);
    }
}

extern "C" void kernel_launch(void* const* d_in, const int* in_sizes, int n_in,
                              void* d_out, int out_size, void* d_ws, size_t ws_size,
                              hipStream_t stream) {
    const float* x    = (const float*)d_in[0];
    const float* Wx_f = (const float*)d_in[1];
    const float* Wh_f = (const float*)d_in[2];
    const float* b_f  = (const float*)d_in[3];
    const float* Wx_b = (const float*)d_in[4];
    const float* Wh_b = (const float*)d_in[5];
    const float* b_b  = (const float*)d_in[6];
    float* out = (float*)d_out;

    char* ws = (char*)d_ws;
    // ws layout: x16 16.78MB | h16 256KB | rh16 128KB | bars 4KB
    __half* x16   = (__half*)ws;
    __half* h16   = (__half*)(ws + (size_t)TT * BB * DD * 2);
    __half* rh16  = (__half*)(ws + (size_t)TT * BB * DD * 2 + (size_t)2 * 2 * BB * UU * 2);
    unsigned* bars = (unsigned*)(ws + (size_t)TT * BB * DD * 2 + (size_t)2 * 2 * BB * UU * 2
                                    + (size_t)2 * BB * UU * 2);

    const long nsetup = (long)TT * BB * DD;  // 8.39M threads covers all init ranges
    bigru_setup<<<(int)((nsetup + 255) / 256), 256, 0, stream>>>(x, x16, h16, bars);
    bigru_persistent<<<2 * NBD, 256, 0, stream>>>(x16, Wx_f, Wh_f, b_f, Wx_b, Wh_b, b_b,
                                                  h16, rh16, bars, out);
}

// Round 2
// 6858.228 us; speedup vs baseline: 1.2208x; 1.2208x over previous
//
#include <hip/hip_runtime.h>
#include <hip/hip_fp16.h>

// BiGRU persistent-kernel, round 5: R3 barrier (wave0 polls, waves parked)
// + block-major h/rh layout (no cross-block false sharing on publishes)
// + R4's LDS-bounce coalesced publishes and vectorized out stores.
// B=64, T=512, D=256, U=512. 128 persistent blocks = 2 dirs x 64 unit-slices.
//
// R4 post-mortem: 4-wave polling + s_sleep REGRESSED (8372us vs R3 6649us) --
// 512 waves hammering 4 flag lines through IC congested the same path
// producers need for store acks. Also WRITE_SIZE=397MB / FETCH_SIZE=677MB
// showed h/rh false sharing ([B][U] layout: 8 blocks' 16B chunks per 128B
// line -> cross-XCD RFO on the publish drain path).
// R5: (a) barrier exactly as verified R3: wave0 polls 64 flags w/ one 256B
// agent load, lane0 acquire (buffer_inv), __syncthreads; no sleep.
// (b) h16/rh16 re-laid out block-major [parity][dir][s][B][8]: each block's
// publish is a contiguous 256B full-line burst per wave; consumer fragment
// k=f*32+quad*8+kk maps to half8 at [(f*4+quad)*64+row]*8 -- still 16B/lane
// coalesced. No line is touched by more than one producer block.

#define BB 64
#define TT 512
#define DD 256
#define UU 512
#define NBD 64        // blocks per direction
#define NJ 8          // units per block (NBD*NJ == UU)
#define LD3U (3*UU)

typedef _Float16 half8 __attribute__((ext_vector_type(8)));
typedef float floatx4 __attribute__((ext_vector_type(4)));
typedef unsigned long long u64;

// ---------------- setup: x -> fp16 [T][B][D]; zero h16 + barrier flags ------
__global__ void bigru_setup(const float* __restrict__ x, __half* __restrict__ x16,
                            __half* __restrict__ h16, unsigned* __restrict__ bars) {
    long idx = (long)blockIdx.x * blockDim.x + threadIdx.x;
    if (idx < (long)TT * BB * DD) {
        int t = (int)(idx / (BB * DD));
        int r = (int)(idx % (BB * DD));
        int b = r / DD;
        int d = r % DD;
        x16[idx] = __float2half(x[((long)b * TT + t) * DD + d]);
    }
    if (idx < 2 * 2 * BB * UU) h16[idx] = __float2half(0.0f);  // both parities, both dirs
    if (idx < 1024) bars[idx] = 0u;                            // both dirs' flag arrays
}

// ---- barrier halves (flag array, no RMW) — verified R3 discipline ----------
__device__ __forceinline__ void bar_arrive(unsigned* flags, int s, unsigned p) {
    // Drain each wave's publishes (ack from IC), then one flag store per block.
    asm volatile("s_waitcnt vmcnt(0)" ::: "memory");
    __syncthreads();
    if (threadIdx.x == 0)
        __hip_atomic_store(&flags[s], p, __ATOMIC_RELAXED, __HIP_MEMORY_SCOPE_AGENT);
}

__device__ __forceinline__ void bar_wait(unsigned* flags, unsigned p) {
    if (threadIdx.x < 64) {
        // Wave 0: lane i polls flags[i]; one coalesced 256B agent load/round.
        for (;;) {
            unsigned v = __hip_atomic_load(&flags[threadIdx.x], __ATOMIC_RELAXED,
                                           __HIP_MEMORY_SCOPE_AGENT);
            if (__ballot(v < p) == 0ull) break;
        }
        if (threadIdx.x == 0)  // acquire: buffer_inv sc1 -> fresh reads below
            (void)__hip_atomic_load(&flags[0], __ATOMIC_ACQUIRE, __HIP_MEMORY_SCOPE_AGENT);
    }
    __syncthreads();
}

// ---------------- persistent BiGRU kernel -----------------------------------
__global__ __launch_bounds__(256, 1) void bigru_persistent(
    const __half* __restrict__ x16,
    const float* __restrict__ Wx_f, const float* __restrict__ Wh_f, const float* __restrict__ b_f,
    const float* __restrict__ Wx_b, const float* __restrict__ Wh_b, const float* __restrict__ b_b,
    __half* __restrict__ h16,    // [parity][dir][s][B][8] fp16, block-major
    __half* __restrict__ rh16,   // [dir][s][B][8] fp16, block-major
    unsigned* __restrict__ bars, // flags: dir0 at [0..64), dir1 at [256..320)
    float* __restrict__ out)     // [B][T][2U] fp32
{
    const int blk  = blockIdx.x;
    const int dir  = blk / NBD;          // 0 = forward, 1 = backward
    const int s    = blk % NBD;
    const int j0   = s * NJ;
    const int tid  = threadIdx.x;
    const int wave = tid >> 6;
    const int lane = tid & 63;
    const int n    = lane & 15;          // MFMA col (C-layout) / A-row (A-layout)
    const int quad = lane >> 4;
    const int mbase = wave * 16;         // this wave's batch-row tile
    const int arow  = mbase + n;         // row this lane loads for A-fragments
    const int koff  = quad * 8;          // k-offset within a K=32 fragment

    const float* Wx = dir ? Wx_b : Wx_f;
    const float* Wh = dir ? Wh_b : Wh_f;
    const float* bv = dir ? b_b  : b_f;

    // Per-wave LDS bounce tiles: transpose lane-scattered gate outputs into
    // row-contiguous chunks for coalesced full-line publishes.
    __shared__ __half lds_rh[4][16][8];   // 1KB: r*h fp16 per wave
    __shared__ __half lds_h[4][16][8];    // 1KB: h fp16 per wave
    __shared__ float  lds_out[4][16][8];  // 2KB: h fp32 for out[]

    // ---- one-time: load weight fragments into registers (fp16) ----
    // Phase-A tile packs u-gate (cols 0..7 -> unit j0+n) and r-gate (cols 8..15).
    half8 WA[24];  // [x;h] @ W(:,u|r), K=768
    half8 W3[8];   // x @ Wx(:,c),      K=256 (cols n>=8 zero-padded)
    half8 WC[16];  // rh @ Wh(:,c),     K=512 (cols n>=8 zero-padded)
    const int colur = (n < 8) ? (j0 + n) : (UU + j0 + (n - 8));
#pragma unroll
    for (int f = 0; f < 24; ++f) {
        const int kb = f * 32 + koff;
#pragma unroll
        for (int kk = 0; kk < 8; ++kk) {
            const int k = kb + kk;
            float v = (k < DD) ? Wx[(long)k * LD3U + colur]
                               : Wh[(long)(k - DD) * LD3U + colur];
            WA[f][kk] = (_Float16)v;
        }
    }
#pragma unroll
    for (int f = 0; f < 8; ++f) {
        const int kb = f * 32 + koff;
#pragma unroll
        for (int kk = 0; kk < 8; ++kk) {
            float v = (n < 8) ? Wx[(long)(kb + kk) * LD3U + 2 * UU + j0 + n] : 0.0f;
            W3[f][kk] = (_Float16)v;
        }
    }
#pragma unroll
    for (int f = 0; f < 16; ++f) {
        const int kb = f * 32 + koff;
#pragma unroll
        for (int kk = 0; kk < 8; ++kk) {
            float v = (n < 8) ? Wh[(long)(kb + kk) * LD3U + 2 * UU + j0 + n] : 0.0f;
            WC[f][kk] = (_Float16)v;
        }
    }
    const float bias_ur = (n < 8) ? bv[j0 + n] : bv[UU + j0 + (n - 8)];
    const float bias_c  = (n < 8) ? bv[2 * UU + j0 + n] : 0.0f;

    // h slice owned by this lane (fp32): h[mbase+quad*4+i][j0+n] for n<8
    float h_own[4] = {0.f, 0.f, 0.f, 0.f};
    float u_keep[4] = {0.f, 0.f, 0.f, 0.f};

    unsigned* flags = bars + dir * 256;
    __half* rhb = rh16 + (long)dir * BB * UU;   // this dir's [s][B][8] region

    // Prologue: x fragments for t=0 + their h-independent MFMAs.
    floatx4 acc_ur = {0.f, 0.f, 0.f, 0.f};
    floatx4 acc_c  = {0.f, 0.f, 0.f, 0.f};
    half8 axx[8];
    {
        const int tx0 = dir ? (TT - 1) : 0;
        const __half* xrow = x16 + ((long)tx0 * BB + arow) * DD + koff;
#pragma unroll
        for (int f = 0; f < 8; ++f) axx[f] = *(const half8*)(xrow + f * 32);
#pragma unroll
        for (int f = 0; f < 8; ++f) {
            acc_ur = __builtin_amdgcn_mfma_f32_16x16x32_f16(axx[f], WA[f], acc_ur, 0, 0, 0);
            acc_c  = __builtin_amdgcn_mfma_f32_16x16x32_f16(axx[f], W3[f], acc_c, 0, 0, 0);
        }
    }

    for (int t = 0; t < TT; ++t) {
        // ---------------- Phase A (critical path: h-part only) ----------------
        // h block-major: element (row, k) at [(k/8)*64 + row]*8 + k%8.
        // Fragment k-range f*32+quad*8..+8 => half8 at [(f*4+quad)*64 + arow]*8.
        const __half* hin = h16 + (long)((t & 1) * 2 + dir) * BB * UU;
        half8 ah[16];
#pragma unroll
        for (int f = 0; f < 16; ++f)
            ah[f] = *(const half8*)(hin + ((long)((8 + f) * 4 + quad) * BB + arow) * 8 - 8L * 4 * BB * 8 / 8);
        // NOTE: the h-part of WA covers k=256..767 of the [x;h] concat, i.e.
        // h-units 0..511 -> fragment index f (0..15) maps to h-k f*32+koff.
#pragma unroll
        for (int f = 0; f < 16; ++f)
            ah[f] = *(const half8*)(hin + ((long)(f * 4 + quad) * BB + arow) * 8);
#pragma unroll
        for (int f = 0; f < 16; ++f)
            acc_ur = __builtin_amdgcn_mfma_f32_16x16x32_f16(ah[f], WA[8 + f], acc_ur, 0, 0, 0);

        // gates: lane(quad,n) holds rows mbase+quad*4+i, col n
#pragma unroll
        for (int i = 0; i < 4; ++i) {
            const float pre = acc_ur[i] + bias_ur;
            const float sg = 1.0f / (1.0f + __expf(-pre));
            // r-lanes (n>=8) need h_own from lane-8 (same quad, col n-8)
            const int src = (n >= 8) ? (lane - 8) : lane;
            const float hov = __shfl(h_own[i], src);
            if (n >= 8) {
                lds_rh[wave][quad * 4 + i][n - 8] = __float2half(sg * hov);
            } else {
                u_keep[i] = sg;
            }
        }
        // In-wave transpose bounce -> one contiguous 256B publish per wave.
        asm volatile("s_waitcnt lgkmcnt(0)" ::: "memory");
        __builtin_amdgcn_sched_barrier(0);
        if (lane < 32) {
            const int r = lane >> 1, hh2 = lane & 1;
            const u64 v = *(const u64*)&lds_rh[wave][r][hh2 * 4];
            __hip_atomic_store((u64*)&rhb[((long)s * BB + mbase + r) * 8 + hh2 * 4], v,
                               __ATOMIC_RELAXED, __HIP_MEMORY_SCOPE_AGENT);
        }
        bar_arrive(flags, s, 2u * (unsigned)t + 1u);
        bar_wait(flags, 2u * (unsigned)t + 1u);

        // ---------------- Phase B ----------------
        half8 arh[16];
#pragma unroll
        for (int f = 0; f < 16; ++f)
            arh[f] = *(const half8*)(rhb + ((long)(f * 4 + quad) * BB + arow) * 8);
#pragma unroll
        for (int f = 0; f < 16; ++f)
            acc_c = __builtin_amdgcn_mfma_f32_16x16x32_f16(arh[f], WC[f], acc_c, 0, 0, 0);

        __half* hout = h16 + (long)(((t + 1) & 1) * 2 + dir) * BB * UU;
        if (n < 8) {
#pragma unroll
            for (int i = 0; i < 4; ++i) {
                float pre = acc_c[i] + bias_c;
                pre = fminf(fmaxf(pre, -15.0f), 15.0f);
                const float e2 = __expf(2.0f * pre);
                const float hh = (e2 - 1.0f) / (e2 + 1.0f);
                const float hn = (1.0f - u_keep[i]) * h_own[i] + u_keep[i] * hh;
                h_own[i] = hn;
                lds_h[wave][quad * 4 + i][n] = __float2half(hn);
                lds_out[wave][quad * 4 + i][n] = hn;
            }
        }
        asm volatile("s_waitcnt lgkmcnt(0)" ::: "memory");
        __builtin_amdgcn_sched_barrier(0);
        if (lane < 32) {
            const int r = lane >> 1, hh2 = lane & 1;
            const u64 v = *(const u64*)&lds_h[wave][r][hh2 * 4];
            __hip_atomic_store((u64*)&hout[((long)s * BB + mbase + r) * 8 + hh2 * 4], v,
                               __ATOMIC_RELAXED, __HIP_MEMORY_SCOPE_AGENT);
        }

        const bool last = (t == TT - 1);
        if (!last) bar_arrive(flags, s, 2u * (unsigned)t + 2u);

        // ---- overlap window (hides the wait for other blocks' h publishes) ----
        {
            // Prefetch x(t+1) first (longest latency, independent).
            const int tn = last ? t : (t + 1);
            const int txn = dir ? (TT - 1 - tn) : tn;
            const __half* xrow = x16 + ((long)txn * BB + arow) * DD + koff;
#pragma unroll
            for (int f = 0; f < 8; ++f) axx[f] = *(const half8*)(xrow + f * 32);

            // out[] store: coalesced 16B rows from the fp32 LDS tile.
            if (lane < 32) {
                const int r = lane >> 1, hh2 = lane & 1;
                const int row = mbase + r;
                *(floatx4*)&out[((long)row * TT + t) * (2 * UU) + (long)dir * UU + j0 + hh2 * 4]
                    = *(const floatx4*)&lds_out[wave][r][hh2 * 4];
            }

            // h-independent MFMAs for t+1.
            floatx4 nacc_ur = {0.f, 0.f, 0.f, 0.f};
            floatx4 nacc_c  = {0.f, 0.f, 0.f, 0.f};
#pragma unroll
            for (int f = 0; f < 8; ++f) {
                nacc_ur = __builtin_amdgcn_mfma_f32_16x16x32_f16(axx[f], WA[f], nacc_ur, 0, 0, 0);
                nacc_c  = __builtin_amdgcn_mfma_f32_16x16x32_f16(axx[f], W3[f], nacc_c, 0, 0, 0);
            }
            acc_ur = nacc_ur;
            acc_c  = nacc_c;
        }

        if (!last) bar_wait(flags, 2u * (unsigned)t + 2u);
    }
}

extern "C" void kernel_launch(void* const* d_in, const int* in_sizes, int n_in,
                              void* d_out, int out_size, void* d_ws, size_t ws_size,
                              hipStream_t stream) {
    const float* x    = (const float*)d_in[0];
    const float* Wx_f = (const float*)d_in[1];
    const float* Wh_f = (const float*)d_in[2];
    const float* b_f  = (const float*)d_in[3];
    const float* Wx_b = (const float*)d_in[4];
    const float* Wh_b = (const float*)d_in[5];
    const float* b_b  = (const float*)d_in[6];
    float* out = (float*)d_out;

    char* ws = (char*)d_ws;
    // ws layout: x16 16.78MB | h16 256KB | rh16 128KB | bars 4KB
    __half* x16   = (__half*)ws;
    __half* h16   = (__half*)(ws + (size_t)TT * BB * DD * 2);
    __half* rh16  = (__half*)(ws + (size_t)TT * BB * DD * 2 + (size_t)2 * 2 * BB * UU * 2);
    unsigned* bars = (unsigned*)(ws + (size_t)TT * BB * DD * 2 + (size_t)2 * 2 * BB * UU * 2
                                    + (size_t)2 * BB * UU * 2);

    const long nsetup = (long)TT * BB * DD;  // 8.39M threads covers all init ranges
    bigru_setup<<<(int)((nsetup + 255) / 256), 256, 0, stream>>>(x, x16, h16, bars);
    bigru_persistent<<<2 * NBD, 256, 0, stream>>>(x16, Wx_f, Wh_f, b_f, Wx_b, Wh_b, b_b,
                                                  h16, rh16, bars, out);
}

// Round 3
// 5801.262 us; speedup vs baseline: 1.4432x; 1.1822x over previous
//
#include <hip/hip_runtime.h>
#include <hip/hip_fp16.h>

// BiGRU persistent-kernel, round 6: no-invalidate consumer path.
// B=64, T=512, D=256, U=512. 128 persistent blocks = 2 dirs x 64 unit-slices.
//
// R5 post-mortem: clean 256B publishes == R3's scattered 2B publishes (6780 vs
// 6649us) -> publish efficiency was never the bottleneck. FETCH_SIZE=677MB
// (1.3MB/step) is the per-XCD h/rh/x working set re-fetched from IC after the
// per-phase agent ACQUIRE (buffer_inv) blows away the XCD L2. R6: delete the
// acquire; read the only cross-block data (h, rh; 128KB) via relaxed AGENT
// atomic u64 loads that bypass stale L1/L2 and read the coherence point
// directly. Producer side unchanged (vmcnt(0) drain -> relaxed agent flag
// store): data is at the coherence point before the flag is visible, so
// coherent loads after flag observation see it. x16/weights/out keep normal
// cached paths and now stay L2-resident (no more invalidates).
// Also: x(t+1) prefetch + its h-independent MFMAs moved into the bar-1 wait
// window (was idle); out[] store remains in the bar-2 window.

#define BB 64
#define TT 512
#define DD 256
#define UU 512
#define NBD 64        // blocks per direction
#define NJ 8          // units per block (NBD*NJ == UU)
#define LD3U (3*UU)

typedef _Float16 half8 __attribute__((ext_vector_type(8)));
typedef float floatx4 __attribute__((ext_vector_type(4)));
typedef unsigned long long u64;

union h8u { half8 h; u64 q[2]; };

// ---------------- setup: x -> fp16 [T][B][D]; zero h16 + barrier flags ------
__global__ void bigru_setup(const float* __restrict__ x, __half* __restrict__ x16,
                            __half* __restrict__ h16, unsigned* __restrict__ bars) {
    long idx = (long)blockIdx.x * blockDim.x + threadIdx.x;
    if (idx < (long)TT * BB * DD) {
        int t = (int)(idx / (BB * DD));
        int r = (int)(idx % (BB * DD));
        int b = r / DD;
        int d = r % DD;
        x16[idx] = __float2half(x[((long)b * TT + t) * DD + d]);
    }
    if (idx < 2 * 2 * BB * UU) h16[idx] = __float2half(0.0f);  // both parities, both dirs
    if (idx < 1024) bars[idx] = 0u;                            // both dirs' flag arrays
}

// ---- barrier halves (flag array, no RMW) -----------------------------------
__device__ __forceinline__ void bar_arrive(unsigned* flags, int s, unsigned p) {
    // Drain each wave's publishes (reach coherence point), then one flag store.
    asm volatile("s_waitcnt vmcnt(0)" ::: "memory");
    __syncthreads();
    if (threadIdx.x == 0)
        __hip_atomic_store(&flags[s], p, __ATOMIC_RELAXED, __HIP_MEMORY_SCOPE_AGENT);
}

__device__ __forceinline__ void bar_wait(unsigned* flags, unsigned p) {
    if (threadIdx.x < 64) {
        // Wave 0: lane i polls flags[i]; one coalesced 256B agent load/round.
        for (;;) {
            unsigned v = __hip_atomic_load(&flags[threadIdx.x], __ATOMIC_RELAXED,
                                           __HIP_MEMORY_SCOPE_AGENT);
            if (__ballot(v < p) == 0ull) break;
        }
        // NO acquire/buffer_inv: all cross-block data is read via coherent
        // (agent-scope atomic) loads below, so the L2 stays warm for x16.
    }
    __syncthreads();
}

// ---- coherent 16B fragment load: two relaxed agent u64 loads ---------------
__device__ __forceinline__ half8 ld_agent_frag(const __half* p) {
    h8u r;
    r.q[0] = __hip_atomic_load((const u64*)p,     __ATOMIC_RELAXED, __HIP_MEMORY_SCOPE_AGENT);
    r.q[1] = __hip_atomic_load((const u64*)p + 1, __ATOMIC_RELAXED, __HIP_MEMORY_SCOPE_AGENT);
    return r.h;
}

// ---------------- persistent BiGRU kernel -----------------------------------
__global__ __launch_bounds__(256, 1) void bigru_persistent(
    const __half* __restrict__ x16,
    const float* __restrict__ Wx_f, const float* __restrict__ Wh_f, const float* __restrict__ b_f,
    const float* __restrict__ Wx_b, const float* __restrict__ Wh_b, const float* __restrict__ b_b,
    __half* __restrict__ h16,    // [parity][dir][s][B][8] fp16, block-major
    __half* __restrict__ rh16,   // [dir][s][B][8] fp16, block-major
    unsigned* __restrict__ bars, // flags: dir0 at [0..64), dir1 at [256..320)
    float* __restrict__ out)     // [B][T][2U] fp32
{
    const int blk  = blockIdx.x;
    const int dir  = blk / NBD;          // 0 = forward, 1 = backward
    const int s    = blk % NBD;
    const int j0   = s * NJ;
    const int tid  = threadIdx.x;
    const int wave = tid >> 6;
    const int lane = tid & 63;
    const int n    = lane & 15;          // MFMA col (C-layout) / A-row (A-layout)
    const int quad = lane >> 4;
    const int mbase = wave * 16;         // this wave's batch-row tile
    const int arow  = mbase + n;         // row this lane loads for A-fragments
    const int koff  = quad * 8;          // k-offset within a K=32 fragment

    const float* Wx = dir ? Wx_b : Wx_f;
    const float* Wh = dir ? Wh_b : Wh_f;
    const float* bv = dir ? b_b  : b_f;

    // Per-wave LDS bounce tiles: transpose lane-scattered gate outputs into
    // row-contiguous chunks for coalesced full-line publishes.
    __shared__ __half lds_rh[4][16][8];   // 1KB: r*h fp16 per wave
    __shared__ __half lds_h[4][16][8];    // 1KB: h fp16 per wave
    __shared__ float  lds_out[4][16][8];  // 2KB: h fp32 for out[]

    // ---- one-time: load weight fragments into registers (fp16) ----
    // Phase-A tile packs u-gate (cols 0..7 -> unit j0+n) and r-gate (cols 8..15).
    half8 WA[24];  // [x;h] @ W(:,u|r), K=768
    half8 W3[8];   // x @ Wx(:,c),      K=256 (cols n>=8 zero-padded)
    half8 WC[16];  // rh @ Wh(:,c),     K=512 (cols n>=8 zero-padded)
    const int colur = (n < 8) ? (j0 + n) : (UU + j0 + (n - 8));
#pragma unroll
    for (int f = 0; f < 24; ++f) {
        const int kb = f * 32 + koff;
#pragma unroll
        for (int kk = 0; kk < 8; ++kk) {
            const int k = kb + kk;
            float v = (k < DD) ? Wx[(long)k * LD3U + colur]
                               : Wh[(long)(k - DD) * LD3U + colur];
            WA[f][kk] = (_Float16)v;
        }
    }
#pragma unroll
    for (int f = 0; f < 8; ++f) {
        const int kb = f * 32 + koff;
#pragma unroll
        for (int kk = 0; kk < 8; ++kk) {
            float v = (n < 8) ? Wx[(long)(kb + kk) * LD3U + 2 * UU + j0 + n] : 0.0f;
            W3[f][kk] = (_Float16)v;
        }
    }
#pragma unroll
    for (int f = 0; f < 16; ++f) {
        const int kb = f * 32 + koff;
#pragma unroll
        for (int kk = 0; kk < 8; ++kk) {
            float v = (n < 8) ? Wh[(long)(kb + kk) * LD3U + 2 * UU + j0 + n] : 0.0f;
            WC[f][kk] = (_Float16)v;
        }
    }
    const float bias_ur = (n < 8) ? bv[j0 + n] : bv[UU + j0 + (n - 8)];
    const float bias_c  = (n < 8) ? bv[2 * UU + j0 + n] : 0.0f;

    // h slice owned by this lane (fp32): h[mbase+quad*4+i][j0+n] for n<8
    float h_own[4] = {0.f, 0.f, 0.f, 0.f};
    float u_keep[4] = {0.f, 0.f, 0.f, 0.f};

    unsigned* flags = bars + dir * 256;
    __half* rhb = rh16 + (long)dir * BB * UU;   // this dir's [s][B][8] region

    // Prologue: x fragments for t=0 + their h-independent MFMAs.
    floatx4 acc_ur = {0.f, 0.f, 0.f, 0.f};
    floatx4 acc_c  = {0.f, 0.f, 0.f, 0.f};
    {
        const int tx0 = dir ? (TT - 1) : 0;
        const __half* xrow = x16 + ((long)tx0 * BB + arow) * DD + koff;
        half8 axx[8];
#pragma unroll
        for (int f = 0; f < 8; ++f) axx[f] = *(const half8*)(xrow + f * 32);
#pragma unroll
        for (int f = 0; f < 8; ++f) {
            acc_ur = __builtin_amdgcn_mfma_f32_16x16x32_f16(axx[f], WA[f], acc_ur, 0, 0, 0);
            acc_c  = __builtin_amdgcn_mfma_f32_16x16x32_f16(axx[f], W3[f], acc_c, 0, 0, 0);
        }
    }

    for (int t = 0; t < TT; ++t) {
        // ---------------- Phase A (critical path: h-part only) ----------------
        // h block-major: fragment k-range f*32+quad*8..+8 lives at
        // half8 [(f*4+quad)*64 + arow]*8. Coherent loads (L2 may be stale).
        const __half* hin = h16 + (long)((t & 1) * 2 + dir) * BB * UU;
        half8 ah[16];
#pragma unroll
        for (int f = 0; f < 16; ++f)
            ah[f] = ld_agent_frag(hin + ((long)(f * 4 + quad) * BB + arow) * 8);
#pragma unroll
        for (int f = 0; f < 16; ++f)
            acc_ur = __builtin_amdgcn_mfma_f32_16x16x32_f16(ah[f], WA[8 + f], acc_ur, 0, 0, 0);

        // gates: lane(quad,n) holds rows mbase+quad*4+i, col n
#pragma unroll
        for (int i = 0; i < 4; ++i) {
            const float pre = acc_ur[i] + bias_ur;
            const float sg = 1.0f / (1.0f + __expf(-pre));
            // r-lanes (n>=8) need h_own from lane-8 (same quad, col n-8)
            const int src = (n >= 8) ? (lane - 8) : lane;
            const float hov = __shfl(h_own[i], src);
            if (n >= 8) {
                lds_rh[wave][quad * 4 + i][n - 8] = __float2half(sg * hov);
            } else {
                u_keep[i] = sg;
            }
        }
        // In-wave transpose bounce -> one contiguous 256B publish per wave.
        asm volatile("s_waitcnt lgkmcnt(0)" ::: "memory");
        __builtin_amdgcn_sched_barrier(0);
        if (lane < 32) {
            const int r = lane >> 1, hh2 = lane & 1;
            const u64 v = *(const u64*)&lds_rh[wave][r][hh2 * 4];
            __hip_atomic_store((u64*)&rhb[((long)s * BB + mbase + r) * 8 + hh2 * 4], v,
                               __ATOMIC_RELAXED, __HIP_MEMORY_SCOPE_AGENT);
        }
        bar_arrive(flags, s, 2u * (unsigned)t + 1u);

        // ---- overlap window 1: x(t+1) prefetch + h-independent MFMAs ----
        const bool last = (t == TT - 1);
        floatx4 nacc_ur = {0.f, 0.f, 0.f, 0.f};
        floatx4 nacc_c  = {0.f, 0.f, 0.f, 0.f};
        {
            const int tn = last ? t : (t + 1);
            const int txn = dir ? (TT - 1 - tn) : tn;
            const __half* xrow = x16 + ((long)txn * BB + arow) * DD + koff;
            half8 axx[8];
#pragma unroll
            for (int f = 0; f < 8; ++f) axx[f] = *(const half8*)(xrow + f * 32);
#pragma unroll
            for (int f = 0; f < 8; ++f) {
                nacc_ur = __builtin_amdgcn_mfma_f32_16x16x32_f16(axx[f], WA[f], nacc_ur, 0, 0, 0);
                nacc_c  = __builtin_amdgcn_mfma_f32_16x16x32_f16(axx[f], W3[f], nacc_c, 0, 0, 0);
            }
        }
        bar_wait(flags, 2u * (unsigned)t + 1u);

        // ---------------- Phase B ----------------
        half8 arh[16];
#pragma unroll
        for (int f = 0; f < 16; ++f)
            arh[f] = ld_agent_frag(rhb + ((long)(f * 4 + quad) * BB + arow) * 8);
#pragma unroll
        for (int f = 0; f < 16; ++f)
            acc_c = __builtin_amdgcn_mfma_f32_16x16x32_f16(arh[f], WC[f], acc_c, 0, 0, 0);

        __half* hout = h16 + (long)(((t + 1) & 1) * 2 + dir) * BB * UU;
        if (n < 8) {
#pragma unroll
            for (int i = 0; i < 4; ++i) {
                float pre = acc_c[i] + bias_c;
                pre = fminf(fmaxf(pre, -15.0f), 15.0f);
                const float e2 = __expf(2.0f * pre);
                const float hh = (e2 - 1.0f) / (e2 + 1.0f);
                const float hn = (1.0f - u_keep[i]) * h_own[i] + u_keep[i] * hh;
                h_own[i] = hn;
                lds_h[wave][quad * 4 + i][n] = __float2half(hn);
                lds_out[wave][quad * 4 + i][n] = hn;
            }
        }
        asm volatile("s_waitcnt lgkmcnt(0)" ::: "memory");
        __builtin_amdgcn_sched_barrier(0);
        if (lane < 32) {
            const int r = lane >> 1, hh2 = lane & 1;
            const u64 v = *(const u64*)&lds_h[wave][r][hh2 * 4];
            __hip_atomic_store((u64*)&hout[((long)s * BB + mbase + r) * 8 + hh2 * 4], v,
                               __ATOMIC_RELAXED, __HIP_MEMORY_SCOPE_AGENT);
        }

        if (!last) bar_arrive(flags, s, 2u * (unsigned)t + 2u);

        // ---- overlap window 2: out[] store (coalesced 16B rows) ----
        if (lane < 32) {
            const int r = lane >> 1, hh2 = lane & 1;
            const int row = mbase + r;
            *(floatx4*)&out[((long)row * TT + t) * (2 * UU) + (long)dir * UU + j0 + hh2 * 4]
                = *(const floatx4*)&lds_out[wave][r][hh2 * 4];
        }
        acc_ur = nacc_ur;
        acc_c  = nacc_c;

        if (!last) bar_wait(flags, 2u * (unsigned)t + 2u);
    }
}

extern "C" void kernel_launch(void* const* d_in, const int* in_sizes, int n_in,
                              void* d_out, int out_size, void* d_ws, size_t ws_size,
                              hipStream_t stream) {
    const float* x    = (const float*)d_in[0];
    const float* Wx_f = (const float*)d_in[1];
    const float* Wh_f = (const float*)d_in[2];
    const float* b_f  = (const float*)d_in[3];
    const float* Wx_b = (const float*)d_in[4];
    const float* Wh_b = (const float*)d_in[5];
    const float* b_b  = (const float*)d_in[6];
    float* out = (float*)d_out;

    char* ws = (char*)d_ws;
    // ws layout: x16 16.78MB | h16 256KB | rh16 128KB | bars 4KB
    __half* x16   = (__half*)ws;
    __half* h16   = (__half*)(ws + (size_t)TT * BB * DD * 2);
    __half* rh16  = (__half*)(ws + (size_t)TT * BB * DD * 2 + (size_t)2 * 2 * BB * UU * 2);
    unsigned* bars = (unsigned*)(ws + (size_t)TT * BB * DD * 2 + (size_t)2 * 2 * BB * UU * 2
                                    + (size_t)2 * BB * UU * 2);

    const long nsetup = (long)TT * BB * DD;  // 8.39M threads covers all init ranges
    bigru_setup<<<(int)((nsetup + 255) / 256), 256, 0, stream>>>(x, x16, h16, bars);
    bigru_persistent<<<2 * NBD, 256, 0, stream>>>(x16, Wx_f, Wh_f, b_f, Wx_b, Wh_b, b_b,
                                                  h16, rh16, bars, out);
}